// Round 1
// baseline (378.295 us; speedup 1.0000x reference)
//
#include <hip/hip_runtime.h>
#include <hip/hip_bf16.h>
#include <hip/hip_fp16.h>

typedef _Float16 half8 __attribute__((ext_vector_type(8)));
typedef float f32x4 __attribute__((ext_vector_type(4)));

#define GM 32768
#define GN 1024
#define GK 1024
#define BM 128
#define BN 128
#define BK 32

#define AX_BLOCKS 1024
#define AW_BLOCKS 32
#define QX_BLOCKS 16384   // 16384*256*8 = 33,554,432
#define QW_BLOCKS 512     // 512*256*8   =  1,048,576

__device__ __forceinline__ float fp8_scale_from_amax(float amax) {
    // exact replication of reference: clip(448/(amax*2+1e-12), 1e-12, 1e12)
    float s = 448.0f / (amax * 2.0f + 1e-12f);
    return fminf(fmaxf(s, 1e-12f), 1e12f);
}

// ---------------- amax (fused x / w) ----------------
__global__ __launch_bounds__(256) void amax_kernel(const float4* __restrict__ x,
                                                   const float4* __restrict__ w,
                                                   unsigned* __restrict__ amax_bits,
                                                   int nx4, int nw4) {
    int b = blockIdx.x;
    const float4* src; int n4; unsigned* slot; int nb; int bl;
    if (b < AX_BLOCKS) { src = x; n4 = nx4; slot = amax_bits + 0; nb = AX_BLOCKS; bl = b; }
    else               { src = w; n4 = nw4; slot = amax_bits + 1; nb = AW_BLOCKS; bl = b - AX_BLOCKS; }
    float m = 0.0f;
    int stride = nb * 256;
    for (int i = bl * 256 + threadIdx.x; i < n4; i += stride) {
        float4 v = src[i];
        m = fmaxf(m, fabsf(v.x)); m = fmaxf(m, fabsf(v.y));
        m = fmaxf(m, fabsf(v.z)); m = fmaxf(m, fabsf(v.w));
    }
    #pragma unroll
    for (int off = 32; off; off >>= 1) m = fmaxf(m, __shfl_xor(m, off));
    if ((threadIdx.x & 63) == 0) atomicMax(slot, __float_as_uint(m)); // m>=0 -> bits monotonic
}

// ---------------- quantize (fused x / w) ----------------
// Stores X8 = rint(clip(x*scale,-448,448)*8) as fp16 (integer <= 1792, exact).
__global__ __launch_bounds__(256) void quant_kernel(const float* __restrict__ x,
                                                    const float* __restrict__ w,
                                                    _Float16* __restrict__ X8,
                                                    _Float16* __restrict__ W8,
                                                    const unsigned* __restrict__ amax_bits) {
    int b = blockIdx.x;
    const float* src; _Float16* dst; int bl; int slot;
    if (b < QX_BLOCKS) { src = x; dst = X8; bl = b; slot = 0; }
    else               { src = w; dst = W8; bl = b - QX_BLOCKS; slot = 1; }
    float amax  = __uint_as_float(amax_bits[slot]);
    float scale = fp8_scale_from_amax(amax);
    size_t base = ((size_t)bl * 256 + threadIdx.x) * 8;
    float4 v0 = *(const float4*)(src + base);
    float4 v1 = *(const float4*)(src + base + 4);
    float vs[8] = {v0.x, v0.y, v0.z, v0.w, v1.x, v1.y, v1.z, v1.w};
    half8 h;
    #pragma unroll
    for (int j = 0; j < 8; ++j) {
        float s = vs[j] * scale;
        s = fminf(fmaxf(s, -448.0f), 448.0f);
        h[j] = (_Float16)rintf(s * 8.0f);   // rintf = round-half-even, matches jnp.round
    }
    *(half8*)(dst + base) = h;
}

// ---------------- GEMM: C = X8 * W8^T * r + bias ----------------
// m97 structure: 128x128 tile, BK=32, 4 waves (2x2), 4x4 frags of 16x16x32 f16 MFMA,
// global_load_lds width-16 staging, 2 barriers/K-step, XCD-chunk swizzle.
__global__ __launch_bounds__(256) void gemm_kernel(const _Float16* __restrict__ A,  // [GM][GK]
                                                   const _Float16* __restrict__ B,  // [GN][GK]
                                                   const float* __restrict__ bias,
                                                   float* __restrict__ C,
                                                   const unsigned* __restrict__ amax_bits) {
    __shared__ _Float16 As[BM * BK];  // 8 KiB, row-major [128][32]
    __shared__ _Float16 Bs[BN * BK];  // 8 KiB

    const int tid  = threadIdx.x;
    const int wid  = tid >> 6;
    const int lane = tid & 63;
    const int wr   = wid >> 1, wc = wid & 1;

    // XCD-aware swizzle: nwg=2048, 8 XCDs, 256 blocks/XCD chunk (bijective)
    const int bid = blockIdx.x;
    const int swz = (bid & 7) * 256 + (bid >> 3);
    const int bn  = swz & 7;        // GN/BN = 8
    const int bm  = swz >> 3;
    const int row0 = bm * BM, col0 = bn * BN;

    f32x4 acc[4][4] = {};

    // staging: issue i in {0,1} covers rows [i*64 + tid/4], col 8*(tid&3)
    const int srow = tid >> 2;
    const int scol = (tid & 3) * 8;
    const _Float16* gA = A + (size_t)(row0 + srow) * GK + scol;
    const _Float16* gB = B + (size_t)(col0 + srow) * GK + scol;

    // wave-uniform LDS dests (HW writes base + lane*16)
    char* ldsA = (char*)As + wid * 1024;
    char* ldsB = (char*)Bs + wid * 1024;

    const int l16 = lane & 15;
    const int kcb = (lane >> 4) * 16;  // byte offset of k-chunk within a 64B row

    for (int kt = 0; kt < GK; kt += BK) {
        __builtin_amdgcn_global_load_lds(
            (const __attribute__((address_space(1))) void*)(gA + kt),
            (__attribute__((address_space(3))) void*)(ldsA), 16, 0, 0);
        __builtin_amdgcn_global_load_lds(
            (const __attribute__((address_space(1))) void*)(gA + kt + (size_t)64 * GK),
            (__attribute__((address_space(3))) void*)(ldsA + 4096), 16, 0, 0);
        __builtin_amdgcn_global_load_lds(
            (const __attribute__((address_space(1))) void*)(gB + kt),
            (__attribute__((address_space(3))) void*)(ldsB), 16, 0, 0);
        __builtin_amdgcn_global_load_lds(
            (const __attribute__((address_space(1))) void*)(gB + kt + (size_t)64 * GK),
            (__attribute__((address_space(3))) void*)(ldsB + 4096), 16, 0, 0);
        __syncthreads();  // compiler drains vmcnt(0) before barrier

        half8 af[4], bf[4];
        #pragma unroll
        for (int mi = 0; mi < 4; ++mi) {
            int r = wr * 64 + mi * 16 + l16;
            af[mi] = *(const half8*)((const char*)As + r * 64 + kcb);
        }
        #pragma unroll
        for (int ni = 0; ni < 4; ++ni) {
            int r = wc * 64 + ni * 16 + l16;
            bf[ni] = *(const half8*)((const char*)Bs + r * 64 + kcb);
        }
        #pragma unroll
        for (int mi = 0; mi < 4; ++mi)
            #pragma unroll
            for (int ni = 0; ni < 4; ++ni)
                acc[mi][ni] = __builtin_amdgcn_mfma_f32_16x16x32_f16(af[mi], bf[ni], acc[mi][ni], 0, 0, 0);
        __syncthreads();  // protect LDS before next stage
    }

    // epilogue: out = acc / (64 * a_scale * w_scale) + bias
    float sa = fp8_scale_from_amax(__uint_as_float(amax_bits[0]));
    float sw = fp8_scale_from_amax(__uint_as_float(amax_bits[1]));
    float r  = 1.0f / (64.0f * sa * sw);

    const int orow = row0 + wr * 64 + (lane >> 4) * 4;
    const int ocol = col0 + wc * 64 + l16;
    #pragma unroll
    for (int mi = 0; mi < 4; ++mi) {
        #pragma unroll
        for (int ni = 0; ni < 4; ++ni) {
            int cc = ocol + ni * 16;
            float bv = bias[cc];
            #pragma unroll
            for (int i = 0; i < 4; ++i) {
                int rr = orow + mi * 16 + i;
                C[(size_t)rr * GN + cc] = acc[mi][ni][i] * r + bv;
            }
        }
    }
}

extern "C" void kernel_launch(void* const* d_in, const int* in_sizes, int n_in,
                              void* d_out, int out_size, void* d_ws, size_t ws_size,
                              hipStream_t stream) {
    const float* x    = (const float*)d_in[0];  // [32768][1024]
    const float* w    = (const float*)d_in[1];  // [1024][1024]
    const float* bias = (const float*)d_in[2];  // [1024]
    float* out        = (float*)d_out;          // [32768][1024]

    unsigned* amax_bits = (unsigned*)d_ws;
    _Float16* X8 = (_Float16*)((char*)d_ws + 256);
    _Float16* W8 = (_Float16*)((char*)d_ws + 256 + (size_t)GM * GK * 2);

    hipMemsetAsync(d_ws, 0, 8, stream);  // zero amax slots (ws is poisoned each call)

    amax_kernel<<<AX_BLOCKS + AW_BLOCKS, 256, 0, stream>>>(
        (const float4*)x, (const float4*)w, amax_bits, GM * GK / 4, GN * GK / 4);

    quant_kernel<<<QX_BLOCKS + QW_BLOCKS, 256, 0, stream>>>(x, w, X8, W8, amax_bits);

    gemm_kernel<<<(GM / BM) * (GN / BN), 256, 0, stream>>>(X8, W8, bias, out, amax_bits);
}